// Round 2
// baseline (563.621 us; speedup 1.0000x reference)
//
#include <hip/hip_runtime.h>
#include <hip/hip_bf16.h>

typedef short bf16x8 __attribute__((ext_vector_type(8)));
typedef float f32x4 __attribute__((ext_vector_type(4)));

#define B_TOT    32768
#define ROWS     64

// LDS layout (bytes)
#define XS_OFF   0        // ushort[64][264]  x tile bf16 (padded)
#define WQ_OFF   33792    // ushort[96][72]   qkv_w^T slice (head, k-chunk) bf16
#define QK_OFF   47616    // ushort[64][104]  per-head q|k|v (32+32+32, pad 8) bf16
#define WP_OFF   33792    // ushort[64][136]  proj_w^T chunk bf16 (overlays WQ+QK)
#define BIAS_OFF 60928    // float[8][8][5]
#define PB_OFF   62208    // float[256]
#define LDS_BYTES 63232

__device__ __forceinline__ unsigned short f2b(float f) {
    union { float f; unsigned u; } v; v.f = f;
    unsigned r = (v.u + 0x7fffu + ((v.u >> 16) & 1u)) >> 16;
    return (unsigned short)r;
}
__device__ __forceinline__ float b2f(unsigned short u) {
    union { unsigned u; float f; } v; v.u = ((unsigned)u) << 16; return v.f;
}

__global__ __launch_bounds__(256)
void ta_fused(const float* __restrict__ x,
              const float* __restrict__ qkv_w,
              const float* __restrict__ proj_w,
              const float* __restrict__ proj_b,
              const float* __restrict__ bias_table,
              const int* __restrict__ rel_index,
              float* __restrict__ out)
{
    __shared__ __align__(16) char smem[LDS_BYTES];
    unsigned short* xs  = (unsigned short*)(smem + XS_OFF);
    unsigned short* wqs = (unsigned short*)(smem + WQ_OFF);
    unsigned short* qks = (unsigned short*)(smem + QK_OFF);
    unsigned short* wps = (unsigned short*)(smem + WP_OFF);
    float* bias_s = (float*)(smem + BIAS_OFF);
    float* pbs    = (float*)(smem + PB_OFF);

    const int tid = threadIdx.x;
    const int l   = tid & 63;
    const int w   = tid >> 6;
    const int l15 = l & 15;
    const int l4  = l >> 4;
    const long wg = blockIdx.x;

    // ---- load x tile (64 rows x 256 f32) -> bf16 LDS ----
    {
        const float* xg = x + wg * (ROWS * 256);
        #pragma unroll
        for (int i = 0; i < 8; ++i) {
            int e = (i * 256 + tid) * 8;
            int row = e >> 8, col = e & 255;
            f32x4 a = *(const f32x4*)(xg + e);
            f32x4 b = *(const f32x4*)(xg + e + 4);
            union { unsigned short u[8]; uint4 v; } pk;
            #pragma unroll
            for (int j = 0; j < 4; ++j) pk.u[j] = f2b(a[j]);
            #pragma unroll
            for (int j = 0; j < 4; ++j) pk.u[4 + j] = f2b(b[j]);
            *(uint4*)&xs[row * 264 + col] = pk.v;
        }
    }
    // ---- relative-position bias table + proj bias (f32) ----
    {
        int n = tid >> 5, m = (tid >> 2) & 7, hh = tid & 3;
        int ri = rel_index[n * 8 + m];
        bias_s[n * 40 + m * 5 + hh] = bias_table[ri * 4 + hh];
        pbs[tid] = proj_b[tid];
    }

    bf16x8 ofrag0, ofrag1, ofrag2, ofrag3;
    const f32x4 zero4 = {0.f, 0.f, 0.f, 0.f};

    #pragma unroll 1
    for (int h = 0; h < 4; ++h) {
        f32x4 acc[6];
        #pragma unroll
        for (int i = 0; i < 6; ++i) acc[i] = zero4;

        #pragma unroll 1
        for (int kc = 0; kc < 4; ++kc) {
            __syncthreads();   // protect wqs from previous chunk's readers
            // stage qkv_w^T slice: 96 rows (q32|k32|v32 of head h) x 64 k, f32 -> bf16
            #pragma unroll
            for (int u = 0; u < 3; ++u) {
                int idx = u * 256 + tid;          // 0..767
                int kl  = idx / 12;               // 0..63
                int oct = idx - kl * 12;          // 0..11
                int cbase = (oct < 4) ? (h * 32 + oct * 8)
                          : (oct < 8) ? (128 + h * 32 + (oct - 4) * 8)
                                      : (256 + h * 32 + (oct - 8) * 8);
                const float* src = qkv_w + (size_t)(kc * 64 + kl) * 384 + cbase;
                f32x4 d0 = *(const f32x4*)src;
                f32x4 d1 = *(const f32x4*)(src + 4);
                #pragma unroll
                for (int j = 0; j < 4; ++j) wqs[(oct * 8 + j) * 72 + kl] = f2b(d0[j]);
                #pragma unroll
                for (int j = 0; j < 4; ++j) wqs[(oct * 8 + 4 + j) * 72 + kl] = f2b(d1[j]);
            }
            __syncthreads();
            // mfma: wave w = m-tile w (16 rows), 6 c-tiles, 2 k-steps
            #pragma unroll
            for (int ks = 0; ks < 2; ++ks) {
                int kk = ks * 32 + l4 * 8;
                bf16x8 a = *(bf16x8*)&xs[(16 * w + l15) * 264 + kc * 64 + kk];
                #pragma unroll
                for (int ct = 0; ct < 6; ++ct) {
                    bf16x8 b = *(bf16x8*)&wqs[(ct * 16 + l15) * 72 + kk];
                    acc[ct] = __builtin_amdgcn_mfma_f32_16x16x32_bf16(a, b, acc[ct], 0, 0, 0);
                }
            }
        }
        // write this head's q|k|v to LDS (bf16). D layout: row=(l>>4)*4+reg, col=l&15
        #pragma unroll
        for (int ct = 0; ct < 6; ++ct) {
            #pragma unroll
            for (int j = 0; j < 4; ++j) {
                int row = 16 * w + l4 * 4 + j;
                qks[row * 104 + ct * 16 + l15] = f2b(acc[ct][j]);
            }
        }
        __syncthreads();

        // ---- attention (head h): lane = (row l&15 of wave tile, d-slice l>>4) ----
        {
            const int r  = 16 * w + l15;
            const int rb = r & ~7;          // batch row base
            const int n  = r & 7;
            const int ds = l4;
            float qf[8];
            {
                bf16x8 qv = *(bf16x8*)&qks[r * 104 + ds * 8];
                #pragma unroll
                for (int j = 0; j < 8; ++j) qf[j] = b2f((unsigned short)qv[j]);
            }
            float sp[8];
            #pragma unroll
            for (int m = 0; m < 8; ++m) {
                bf16x8 kv = *(bf16x8*)&qks[(rb + m) * 104 + 32 + ds * 8];
                float s = 0.f;
                #pragma unroll
                for (int j = 0; j < 8; ++j) s += qf[j] * b2f((unsigned short)kv[j]);
                sp[m] = s;
            }
            #pragma unroll
            for (int m = 0; m < 8; ++m) {   // reduce over the 4 d-slices
                sp[m] += __shfl_xor(sp[m], 16);
                sp[m] += __shfl_xor(sp[m], 32);
            }
            float mx = -1e30f;
            #pragma unroll
            for (int m = 0; m < 8; ++m) {
                sp[m] = sp[m] * 0.125f + bias_s[n * 40 + m * 5 + h];
                mx = fmaxf(mx, sp[m]);
            }
            float sum = 0.f;
            #pragma unroll
            for (int m = 0; m < 8; ++m) { sp[m] = __expf(sp[m] - mx); sum += sp[m]; }
            float inv = 1.f / sum;
            float o[8] = {0.f,0.f,0.f,0.f,0.f,0.f,0.f,0.f};
            #pragma unroll
            for (int m = 0; m < 8; ++m) {
                bf16x8 vv = *(bf16x8*)&qks[(rb + m) * 104 + 64 + ds * 8];
                #pragma unroll
                for (int j = 0; j < 8; ++j) o[j] += sp[m] * b2f((unsigned short)vv[j]);
            }
            bf16x8 of;
            #pragma unroll
            for (int j = 0; j < 8; ++j) of[j] = (short)f2b(o[j] * inv);
            if      (h == 0) ofrag0 = of;
            else if (h == 1) ofrag1 = of;
            else if (h == 2) ofrag2 = of;
            else             ofrag3 = of;
        }
    }

    __syncthreads();   // all attention reads done before wps overlays qks

    // ---- GEMM2: out = o @ proj_w + proj_b; A-frags are ofrag0..3 (k-step = head) ----
    f32x4 acc2[16];
    #pragma unroll
    for (int i = 0; i < 16; ++i) acc2[i] = zero4;

    #pragma unroll 1
    for (int cc = 0; cc < 4; ++cc) {
        if (cc) __syncthreads();
        #pragma unroll
        for (int u = 0; u < 4; ++u) {
            int idx = u * 256 + tid;     // 0..1023
            int k   = idx >> 3;          // 0..127
            int o8  = idx & 7;
            const float* src = proj_w + (size_t)k * 256 + cc * 64 + o8 * 8;
            f32x4 d0 = *(const f32x4*)src;
            f32x4 d1 = *(const f32x4*)(src + 4);
            #pragma unroll
            for (int j = 0; j < 4; ++j) wps[(o8 * 8 + j) * 136 + k] = f2b(d0[j]);
            #pragma unroll
            for (int j = 0; j < 4; ++j) wps[(o8 * 8 + 4 + j) * 136 + k] = f2b(d1[j]);
        }
        __syncthreads();
        #pragma unroll
        for (int ctl = 0; ctl < 4; ++ctl) {
            #pragma unroll
            for (int ks = 0; ks < 4; ++ks) {
                bf16x8 b = *(bf16x8*)&wps[(ctl * 16 + l15) * 136 + ks * 32 + l4 * 8];
                bf16x8 a = (ks == 0) ? ofrag0 : (ks == 1) ? ofrag1 : (ks == 2) ? ofrag2 : ofrag3;
                acc2[cc * 4 + ctl] = __builtin_amdgcn_mfma_f32_16x16x32_bf16(a, b, acc2[cc * 4 + ctl], 0, 0, 0);
            }
        }
    }

    // epilogue: direct f32 global stores (+proj_b), no LDS staging
    {
        float* og = out + wg * (ROWS * 256);
        #pragma unroll
        for (int cc = 0; cc < 4; ++cc)
          #pragma unroll
          for (int ctl = 0; ctl < 4; ++ctl)
            #pragma unroll
            for (int j = 0; j < 4; ++j) {
                int row = 16 * w + l4 * 4 + j;
                int col = cc * 64 + ctl * 16 + l15;
                og[row * 256 + col] = acc2[cc * 4 + ctl][j] + pbs[col];
            }
    }
}

extern "C" void kernel_launch(void* const* d_in, const int* in_sizes, int n_in,
                              void* d_out, int out_size, void* d_ws, size_t ws_size,
                              hipStream_t stream)
{
    (void)in_sizes; (void)n_in; (void)d_ws; (void)ws_size; (void)out_size;
    const float* x  = (const float*)d_in[0];
    const float* qw = (const float*)d_in[1];
    const float* pw = (const float*)d_in[2];
    const float* pb = (const float*)d_in[3];
    const float* bt = (const float*)d_in[4];
    const int*   ri = (const int*)d_in[5];
    float* o = (float*)d_out;

    dim3 grid(B_TOT / 8);
    dim3 block(256);
    hipLaunchKernelGGL(ta_fused, grid, block, 0, stream, x, qw, pw, pb, bt, ri, o);
}

// Round 3
// 237.238 us; speedup vs baseline: 2.3758x; 2.3758x over previous
//
#include <hip/hip_runtime.h>
#include <hip/hip_bf16.h>

typedef short bf16x8 __attribute__((ext_vector_type(8)));
typedef float f32x4 __attribute__((ext_vector_type(4)));

#define B_TOT    32768
#define ROWS     64

// ---- workspace layout (bytes): bf16 W^T, written by prep_w each call ----
#define WSQ_ELT  0         // ushort [384][256]  qkv_w^T
#define WSP_ELT  98304     // ushort [256][128]  proj_w^T
#define WS_BYTES 262144

// ---- main-kernel LDS layout (bytes) ----
#define WQ_OFF   0         // ushort[96][136]  qkv_w^T slice (head, K-half)   26112
#define QK_OFF   26112     // ushort[64][104]  per-head q|k|v                 13312
#define BIAS_OFF 39424     // float[8][8][5]                                   1280
#define PB_OFF   40704     // float[256]                                       1024
#define OUT_OFF  0         // float[32][260] epilogue overlay                 33280
#define LDS_BYTES 41728

__device__ __forceinline__ unsigned short f2b(float f) {
    union { float f; unsigned u; } v; v.f = f;
    unsigned r = (v.u + 0x7fffu + ((v.u >> 16) & 1u)) >> 16;
    return (unsigned short)r;
}
__device__ __forceinline__ float b2f(unsigned short u) {
    union { unsigned u; float f; } v; v.u = ((unsigned)u) << 16; return v.f;
}

// ---------- pre-kernel: W (f32, row-major) -> W^T (bf16) in ws ----------
// qkv_w: [256][384] -> wsq [384][256];  proj_w: [128][256] -> wsp [256][128]
__global__ __launch_bounds__(256)
void prep_w(const float* __restrict__ qkv_w, const float* __restrict__ proj_w,
            unsigned short* __restrict__ ws)
{
    __shared__ float tile[64][65];
    const int bid = blockIdx.x;
    const float* src; unsigned short* dst; int ldw, ldk, tr0, tc0;
    if (bid < 24) {            // qkv: 4 k-tiles x 6 c-tiles
        int kr = bid / 6, cg = bid % 6;
        src = qkv_w; dst = ws + WSQ_ELT; ldw = 384; ldk = 256;
        tr0 = kr * 64; tc0 = cg * 64;
    } else {                   // proj: 2 k-tiles x 4 c-tiles
        int b = bid - 24; int kr = b / 4, cg = b % 4;
        src = proj_w; dst = ws + WSP_ELT; ldw = 256; ldk = 128;
        tr0 = kr * 64; tc0 = cg * 64;
    }
    const int t = threadIdx.x;
    #pragma unroll
    for (int i = 0; i < 16; ++i) {
        int idx = i * 256 + t;
        int r = idx >> 6, c = idx & 63;
        tile[r][c] = src[(size_t)(tr0 + r) * ldw + tc0 + c];
    }
    __syncthreads();
    #pragma unroll
    for (int i = 0; i < 2; ++i) {
        int idx = i * 256 + t;          // 0..511
        int c = idx >> 3, r0 = (idx & 7) * 8;
        union { unsigned short u[8]; uint4 v; } pk;
        #pragma unroll
        for (int j = 0; j < 8; ++j) pk.u[j] = f2b(tile[r0 + j][c]);
        *(uint4*)&dst[(size_t)(tc0 + c) * ldk + tr0 + r0] = pk.v;
    }
}

// ---------- main fused kernel ----------
__global__ __launch_bounds__(256)
void ta_fused(const float* __restrict__ x,
              const unsigned short* __restrict__ ws,
              const float* __restrict__ proj_b,
              const float* __restrict__ bias_table,
              const int* __restrict__ rel_index,
              float* __restrict__ out)
{
    __shared__ __align__(16) char smem[LDS_BYTES];
    unsigned short* wqs = (unsigned short*)(smem + WQ_OFF);
    unsigned short* qks = (unsigned short*)(smem + QK_OFF);
    float* bias_s = (float*)(smem + BIAS_OFF);
    float* pbs    = (float*)(smem + PB_OFF);
    float* outs   = (float*)(smem + OUT_OFF);

    const unsigned short* wsq = ws + WSQ_ELT;
    const unsigned short* wsp = ws + WSP_ELT;

    const int tid = threadIdx.x;
    const int l   = tid & 63;
    const int w   = tid >> 6;
    const int l15 = l & 15;
    const int l4  = l >> 4;
    const long wg = blockIdx.x;

    // ---- x A-fragments straight to registers (x read exactly once) ----
    bf16x8 af[8];
    {
        const float* xg = x + wg * (ROWS * 256) + (size_t)(16 * w + l15) * 256;
        #pragma unroll
        for (int s = 0; s < 8; ++s) {
            f32x4 d0 = *(const f32x4*)(xg + s * 32 + l4 * 8);
            f32x4 d1 = *(const f32x4*)(xg + s * 32 + l4 * 8 + 4);
            union { unsigned short u[8]; bf16x8 v; } pk;
            #pragma unroll
            for (int j = 0; j < 4; ++j) pk.u[j] = f2b(d0[j]);
            #pragma unroll
            for (int j = 0; j < 4; ++j) pk.u[4 + j] = f2b(d1[j]);
            af[s] = pk.v;
        }
    }
    // ---- bias table + proj bias ----
    {
        int n = tid >> 5, m = (tid >> 2) & 7, hh = tid & 3;
        int ri = rel_index[n * 8 + m];
        bias_s[n * 40 + m * 5 + hh] = bias_table[ri * 4 + hh];
        pbs[tid] = proj_b[tid];
    }

    bf16x8 ofrag0, ofrag1, ofrag2, ofrag3;
    const f32x4 zero4 = {0.f, 0.f, 0.f, 0.f};

    #pragma unroll 1
    for (int h = 0; h < 4; ++h) {
        f32x4 acc[6];
        #pragma unroll
        for (int i = 0; i < 6; ++i) acc[i] = zero4;

        #pragma unroll            // MUST be static: af[] indexing
        for (int c = 0; c < 2; ++c) {
            __syncthreads();      // wqs safe to overwrite
            // stage qkv_w^T slice: 96 rows x 128 k (bf16, straight copy)
            #pragma unroll
            for (int u = 0; u < 6; ++u) {
                int idx = u * 256 + tid;          // 0..1535
                int rr = idx >> 4, seg = idx & 15;
                int p = rr >> 5, within = rr & 31;
                uint4 d = *(const uint4*)&wsq[(size_t)(p * 128 + h * 32 + within) * 256 + c * 128 + seg * 8];
                *(uint4*)&wqs[rr * 136 + seg * 8] = d;
            }
            __syncthreads();
            #pragma unroll
            for (int ks2 = 0; ks2 < 4; ++ks2) {
                bf16x8 a = af[c * 4 + ks2];
                #pragma unroll
                for (int ct = 0; ct < 6; ++ct) {
                    bf16x8 b = *(bf16x8*)&wqs[(ct * 16 + l15) * 136 + ks2 * 32 + l4 * 8];
                    acc[ct] = __builtin_amdgcn_mfma_f32_16x16x32_bf16(a, b, acc[ct], 0, 0, 0);
                }
            }
        }
        // this head's q|k|v -> LDS (bf16). D layout: row=(l>>4)*4+reg, col=l&15
        #pragma unroll
        for (int ct = 0; ct < 6; ++ct) {
            #pragma unroll
            for (int j = 0; j < 4; ++j) {
                int row = 16 * w + l4 * 4 + j;
                qks[row * 104 + ct * 16 + l15] = f2b(acc[ct][j]);
            }
        }
        __syncthreads();

        // ---- attention (head h): lane = (row l&15, d-slice l>>4) ----
        {
            const int r  = 16 * w + l15;
            const int rb = r & ~7;
            const int n  = r & 7;
            const int ds = l4;
            float qf[8];
            {
                bf16x8 qv = *(bf16x8*)&qks[r * 104 + ds * 8];
                #pragma unroll
                for (int j = 0; j < 8; ++j) qf[j] = b2f((unsigned short)qv[j]);
            }
            float sp[8];
            #pragma unroll
            for (int m = 0; m < 8; ++m) {
                bf16x8 kv = *(bf16x8*)&qks[(rb + m) * 104 + 32 + ds * 8];
                float s = 0.f;
                #pragma unroll
                for (int j = 0; j < 8; ++j) s += qf[j] * b2f((unsigned short)kv[j]);
                sp[m] = s;
            }
            #pragma unroll
            for (int m = 0; m < 8; ++m) {
                sp[m] += __shfl_xor(sp[m], 16);
                sp[m] += __shfl_xor(sp[m], 32);
            }
            float mx = -1e30f;
            #pragma unroll
            for (int m = 0; m < 8; ++m) {
                sp[m] = sp[m] * 0.125f + bias_s[n * 40 + m * 5 + h];
                mx = fmaxf(mx, sp[m]);
            }
            float sum = 0.f;
            #pragma unroll
            for (int m = 0; m < 8; ++m) { sp[m] = __expf(sp[m] - mx); sum += sp[m]; }
            float inv = 1.f / sum;
            float o[8] = {0.f,0.f,0.f,0.f,0.f,0.f,0.f,0.f};
            #pragma unroll
            for (int m = 0; m < 8; ++m) {
                bf16x8 vv = *(bf16x8*)&qks[(rb + m) * 104 + 64 + ds * 8];
                #pragma unroll
                for (int j = 0; j < 8; ++j) o[j] += sp[m] * b2f((unsigned short)vv[j]);
            }
            bf16x8 of;
            #pragma unroll
            for (int j = 0; j < 8; ++j) of[j] = (short)f2b(o[j] * inv);
            if      (h == 0) ofrag0 = of;
            else if (h == 1) ofrag1 = of;
            else if (h == 2) ofrag2 = of;
            else             ofrag3 = of;
        }
    }

    // ---- GEMM2: out = o @ proj_w + proj_b ----
    f32x4 acc2[16];
    #pragma unroll
    for (int i = 0; i < 16; ++i) acc2[i] = zero4;

    #pragma unroll               // MUST be static: acc2[] indexing
    for (int cc = 0; cc < 4; ++cc) {
        __syncthreads();         // wps region (=wqs) safe to overwrite
        #pragma unroll
        for (int u = 0; u < 4; ++u) {
            int idx = u * 256 + tid;          // 0..1023
            int rr = idx >> 4, seg = idx & 15;
            uint4 d = *(const uint4*)&wsp[(size_t)(cc * 64 + rr) * 128 + seg * 8];
            *(uint4*)&wqs[rr * 136 + seg * 8] = d;
        }
        __syncthreads();
        #pragma unroll
        for (int ctl = 0; ctl < 4; ++ctl) {
            #pragma unroll
            for (int ks = 0; ks < 4; ++ks) {
                bf16x8 b = *(bf16x8*)&wqs[(ctl * 16 + l15) * 136 + ks * 32 + l4 * 8];
                bf16x8 a = (ks == 0) ? ofrag0 : (ks == 1) ? ofrag1 : (ks == 2) ? ofrag2 : ofrag3;
                acc2[cc * 4 + ctl] = __builtin_amdgcn_mfma_f32_16x16x32_bf16(a, b, acc2[cc * 4 + ctl], 0, 0, 0);
            }
        }
    }

    // ---- epilogue: LDS-staged, fully coalesced f32 stores ----
    #pragma unroll
    for (int half = 0; half < 2; ++half) {
        __syncthreads();         // outs overlay safe
        if ((w < 2) == (half == 0)) {
            #pragma unroll
            for (int cc = 0; cc < 4; ++cc)
              #pragma unroll
              for (int ctl = 0; ctl < 4; ++ctl)
                #pragma unroll
                for (int j = 0; j < 4; ++j) {
                    int row = 16 * (w & 1) + l4 * 4 + j;
                    int col = cc * 64 + ctl * 16 + l15;
                    outs[row * 260 + col] = acc2[cc * 4 + ctl][j] + pbs[col];
                }
        }
        __syncthreads();
        float* og = out + wg * (ROWS * 256) + half * (32 * 256);
        #pragma unroll
        for (int i = 0; i < 4; ++i) {
            int f0 = (i * 256 + tid) * 8;     // 0..8191
            int row = f0 >> 8, col = f0 & 255;
            f32x4 v0 = *(f32x4*)&outs[row * 260 + col];
            f32x4 v1 = *(f32x4*)&outs[row * 260 + col + 4];
            *(f32x4*)(og + f0)     = v0;
            *(f32x4*)(og + f0 + 4) = v1;
        }
    }
}

extern "C" void kernel_launch(void* const* d_in, const int* in_sizes, int n_in,
                              void* d_out, int out_size, void* d_ws, size_t ws_size,
                              hipStream_t stream)
{
    (void)in_sizes; (void)n_in; (void)ws_size; (void)out_size;
    const float* x  = (const float*)d_in[0];
    const float* qw = (const float*)d_in[1];
    const float* pw = (const float*)d_in[2];
    const float* pb = (const float*)d_in[3];
    const float* bt = (const float*)d_in[4];
    const int*   ri = (const int*)d_in[5];
    float* o = (float*)d_out;
    unsigned short* ws = (unsigned short*)d_ws;

    hipLaunchKernelGGL(prep_w, dim3(32), dim3(256), 0, stream, qw, pw, ws);
    hipLaunchKernelGGL(ta_fused, dim3(B_TOT / 8), dim3(256), 0, stream,
                       x, ws, pb, bt, ri, o);
}